// Round 1
// baseline (138.328 us; speedup 1.0000x reference)
//
#include <hip/hip_runtime.h>

#define WIDTH   256
#define HEIGHT  256
#define NG      8192
#define TILE_SZ 16
#define MINW    1e-6f

__global__ __launch_bounds__(256) void raster_kernel(
    const float* __restrict__ pts,    // [N,2]
    const float* __restrict__ icov,   // [N,2,2]  [[a,b],[b,c]]
    const float* __restrict__ rad,    // [N]
    const float* __restrict__ cols,   // [N,3]
    const float* __restrict__ opac,   // [N] logits
    float* __restrict__ out)          // [W,H,3], idx = (x*H+y)*3+c
{
    __shared__ unsigned short s_list[NG];        // 16 KB: ordered surviving indices
    __shared__ unsigned long long s_wmask[4];
    __shared__ float smx[256], smy[256], sa[256], sb[256], sc2[256],
                     sop[256], scr[256], scg[256], scb[256];   // 9 KB chunk stage

    const int tid  = threadIdx.x;
    const int lane = tid & 63;
    const int wave = tid >> 6;
    const float tx0 = (float)(blockIdx.x * TILE_SZ);
    const float ty0 = (float)(blockIdx.y * TILE_SZ);
    const float tx1 = tx0 + (float)TILE_SZ;
    const float ty1 = ty0 + (float)TILE_SZ;

    // ---- Phase 1: ordered compaction of gaussians whose bbox hits this tile
    int count = 0;                                // block-uniform running total
    for (int batch = 0; batch < NG; batch += 256) {
        const int g = batch + tid;
        const float2 p = ((const float2*)pts)[g];
        const float  r = rad[g];
        // exact reference test: floor(mx-r)<=tx0+T && ceil(mx+r)>=tx0 && ...
        bool hit = (floorf(p.x - r) <= tx1) & (ceilf(p.x + r) >= tx0)
                 & (floorf(p.y - r) <= ty1) & (ceilf(p.y + r) >= ty0);
        unsigned long long m = __ballot(hit);
        if (lane == 0) s_wmask[wave] = m;
        __syncthreads();
        int off = count, total = 0;
        #pragma unroll
        for (int w = 0; w < 4; ++w) {
            int pc = __popcll(s_wmask[w]);
            if (w < wave) off += pc;
            total += pc;
        }
        if (hit)
            s_list[off + __popcll(m & ((1ull << lane) - 1ull))] = (unsigned short)g;
        count += total;
        __syncthreads();                          // protect s_wmask + s_list reuse
    }

    // ---- Phase 2: exact sequential front-to-back composite over the list
    const int lx = tid >> 4, ly = tid & 15;       // ly fastest -> coalesced store
    const float fx = tx0 + (float)lx;
    const float fy = ty0 + (float)ly;
    float T = 1.0f, cr = 0.0f, cg = 0.0f, cb = 0.0f;
    bool dead = false;

    for (int base = 0; base < count; base += 256) {
        const int n = min(256, count - base);
        if (tid < n) {
            const int g = s_list[base + tid];
            const float2 p = ((const float2*)pts)[g];
            smx[tid] = p.x;  smy[tid] = p.y;
            const float4 ic = ((const float4*)icov)[g];
            sa[tid] = ic.x;  sb[tid] = ic.y;  sc2[tid] = ic.w;
            sop[tid] = 1.0f / (1.0f + __expf(-opac[g]));   // sigmoid
            scr[tid] = cols[3*g];  scg[tid] = cols[3*g+1];  scb[tid] = cols[3*g+2];
        }
        __syncthreads();
        if (!dead) {
            for (int j = 0; j < n; ++j) {
                const float dx = fx - smx[j];
                const float dy = fy - smy[j];
                const float q  = sa[j]*dx*dx + 2.0f*sb[j]*(dx*dy) + sc2[j]*dy*dy;
                const float alpha = __expf(-0.5f * q) * sop[j];
                const float Tn = T * (1.0f - alpha);
                if (Tn >= MINW) {                 // reference include test
                    const float w = T * alpha;
                    cr += w * scr[j];  cg += w * scg[j];  cb += w * scb[j];
                    T = Tn;
                } else {                          // T non-increasing => done forever
                    dead = true;
                    break;
                }
            }
        }
        // block-uniform early exit + barrier protecting next chunk's LDS overwrite
        if (__syncthreads_count(dead ? 1 : 0) == 256) break;
    }

    const int x = blockIdx.x * TILE_SZ + lx;
    const int y = blockIdx.y * TILE_SZ + ly;
    const int o = (x * HEIGHT + y) * 3;
    out[o] = cr;  out[o + 1] = cg;  out[o + 2] = cb;
}

extern "C" void kernel_launch(void* const* d_in, const int* in_sizes, int n_in,
                              void* d_out, int out_size, void* d_ws, size_t ws_size,
                              hipStream_t stream) {
    const float* pts  = (const float*)d_in[0];
    const float* icov = (const float*)d_in[1];
    const float* rad  = (const float*)d_in[2];
    const float* cols = (const float*)d_in[3];
    const float* opac = (const float*)d_in[4];
    float* out = (float*)d_out;
    dim3 grid(WIDTH / TILE_SZ, HEIGHT / TILE_SZ);   // 16x16 tiles
    raster_kernel<<<grid, dim3(256), 0, stream>>>(pts, icov, rad, cols, opac, out);
}

// Round 2
// 90.614 us; speedup vs baseline: 1.5266x; 1.5266x over previous
//
#include <hip/hip_runtime.h>

#define WIDTH   256
#define HEIGHT  256
#define NG      8192
#define TILE_SZ 16
#define MINW    1e-6f
#define NBATCH  32          // NG / 256
#define CHUNK   256

__global__ __launch_bounds__(256) void raster_kernel(
    const float* __restrict__ pts,    // [N,2]
    const float* __restrict__ icov,   // [N,2,2]  [[a,b],[b,c]]
    const float* __restrict__ rad,    // [N]
    const float* __restrict__ cols,   // [N,3]
    const float* __restrict__ opac,   // [N] logits
    float* __restrict__ out)          // [W,H,3], idx = (x*H+y)*3+c
{
    __shared__ unsigned long long s_ball[NBATCH * 4];   // per-batch per-wave ballots (1 KB)
    __shared__ int s_pfx[2][NBATCH * 4];                // ping-pong inclusive scan (1 KB)
    __shared__ unsigned short s_list[NG];               // ordered surviving indices (16 KB)
    __shared__ float4 s_g[CHUNK * 3];                   // packed gaussian chunk (12 KB)

    const int tid  = threadIdx.x;
    const int lane = tid & 63;
    const int wave = tid >> 6;
    const float tx0 = (float)(blockIdx.x * TILE_SZ);
    const float ty0 = (float)(blockIdx.y * TILE_SZ);
    const float tx1 = tx0 + (float)TILE_SZ;
    const float ty1 = ty0 + (float)TILE_SZ;

    // ---- Phase 1: barrier-free hit testing (ballots to distinct slots), then one scan
    unsigned int hitbits = 0;
    for (int b = 0; b < NBATCH; ++b) {
        const int g = b * 256 + tid;
        const float2 p = ((const float2*)pts)[g];
        const float  r = rad[g];
        bool hit = (floorf(p.x - r) <= tx1) & (ceilf(p.x + r) >= tx0)
                 & (floorf(p.y - r) <= ty1) & (ceilf(p.y + r) >= ty0);
        unsigned long long m = __ballot(hit);
        if (lane == 0) s_ball[b * 4 + wave] = m;
        if (hit) hitbits |= (1u << b);
    }
    __syncthreads();

    // inclusive prefix over popcounts of the 128 ballots (ordered: batch-major, wave minor)
    if (tid < 128) s_pfx[0][tid] = __popcll(s_ball[tid]);
    __syncthreads();
    int src = 0;
    for (int d = 1; d < 128; d <<= 1) {
        if (tid < 128) {
            int v = s_pfx[src][tid];
            if (tid >= d) v += s_pfx[src][tid - d];
            s_pfx[src ^ 1][tid] = v;
        }
        __syncthreads();
        src ^= 1;
    }
    const int count = s_pfx[src][127];

    // scatter this thread's hits into the ordered list
    {
        unsigned int hb = hitbits;
        const unsigned long long ltmask = (lane == 63) ? ~0ull >> 1 : (1ull << lane) - 1ull;
        while (hb) {
            const int b = __ffs(hb) - 1;  hb &= hb - 1;
            const int idx = b * 4 + wave;
            const unsigned long long m = s_ball[idx];
            const int base = (idx == 0) ? 0 : s_pfx[src][idx - 1];
            s_list[base + __popcll(m & ltmask)] = (unsigned short)(b * 256 + tid);
        }
    }
    __syncthreads();

    // ---- Phase 2: branch-free predicated composite (exact vs reference: the
    // reference's prefix product decays unconditionally; the gate only zeroes w)
    const int lx = tid >> 4, ly = tid & 15;
    const float fx = tx0 + (float)lx;
    const float fy = ty0 + (float)ly;
    float T = 1.0f, accr = 0.0f, accg = 0.0f, accb = 0.0f;
    const float kc = -0.72134752044f;                   // -0.5 * log2(e), folded into a,b,c

    for (int base = 0; base < count; base += CHUNK) {
        const int n = min(CHUNK, count - base);
        if (tid < n) {
            const int g = s_list[base + tid];
            const float2 p = ((const float2*)pts)[g];
            const float4 ic = ((const float4*)icov)[g];
            const float op = 1.0f / (1.0f + __expf(-opac[g]));
            s_g[tid * 3 + 0] = make_float4(p.x, p.y, kc * ic.x, 2.0f * kc * ic.y);
            s_g[tid * 3 + 1] = make_float4(kc * ic.w, op, cols[3 * g], cols[3 * g + 1]);
            s_g[tid * 3 + 2] = make_float4(cols[3 * g + 2], 0.f, 0.f, 0.f);
        }
        __syncthreads();

        for (int j0 = 0; j0 < n; j0 += 32) {
            if (__ballot(T >= MINW) == 0ull) break;      // whole wave dead -> skip group
            const int jend = min(j0 + 32, n);
            #pragma unroll 8
            for (int j = j0; j < jend; ++j) {
                const float4 g0 = s_g[j * 3 + 0];
                const float4 g1 = s_g[j * 3 + 1];
                const float cbv = s_g[j * 3 + 2].x;
                const float dx = fx - g0.x;
                const float dy = fy - g0.y;
                const float q  = (g0.z * dx) * dx + (g0.w * dx) * dy + (g1.x * dy) * dy;
                const float alpha = g1.y * __builtin_amdgcn_exp2f(q);   // op * 2^(kc*Q)
                const float Tn = T * (1.0f - alpha);
                const float w  = (Tn >= MINW) ? T * alpha : 0.0f;
                accr = fmaf(w, g1.z, accr);
                accg = fmaf(w, g1.w, accg);
                accb = fmaf(w, cbv, accb);
                T = Tn;                                  // unconditional, like reference
            }
        }
        if (__syncthreads_count(T < MINW) == 256) break; // all 256 pixels saturated
    }

    const int x = blockIdx.x * TILE_SZ + lx;
    const int y = blockIdx.y * TILE_SZ + ly;
    const int o = (x * HEIGHT + y) * 3;
    out[o] = accr;  out[o + 1] = accg;  out[o + 2] = accb;
}

extern "C" void kernel_launch(void* const* d_in, const int* in_sizes, int n_in,
                              void* d_out, int out_size, void* d_ws, size_t ws_size,
                              hipStream_t stream) {
    const float* pts  = (const float*)d_in[0];
    const float* icov = (const float*)d_in[1];
    const float* rad  = (const float*)d_in[2];
    const float* cols = (const float*)d_in[3];
    const float* opac = (const float*)d_in[4];
    float* out = (float*)d_out;
    dim3 grid(WIDTH / TILE_SZ, HEIGHT / TILE_SZ);
    raster_kernel<<<grid, dim3(256), 0, stream>>>(pts, icov, rad, cols, opac, out);
}